// Round 16
// baseline (928.544 us; speedup 1.0000x reference)
//
#include <hip/hip_runtime.h>
#include <hip/hip_bf16.h>

// WindowAttention (Swin) on MI355X — round 16
//   Base = R15 (918us). Change: qkv GEMM -> 256x128 block, 8 waves of 64x64
//   (best LDS-bytes-per-FLOP: 0.031), 3-buf 72KB, vmcnt(6) depth-2, and
//   chunk^(row&3) XOR swizzle on BOTH gload-source and ds_read (8-way -> 4-way
//   conflict, max fix at 64B rows). Diagnosis: GEMM is LDS-read-BW bound
//   (48KB read / 16KB staged per block-step ~ 900-1100 cyc vs MFMA 320).
//   proj keeps R15 kernel; attn/cvt/bm = R15 verbatim.

typedef __attribute__((ext_vector_type(8))) short bf16x8;
typedef __attribute__((ext_vector_type(4))) float f32x4;

#define SEQ_N  49
#define CH     384
#define QKV_N  1152
#define UNIT_ROWS 3136   // 64 windows * 49 rows
#define BM_ELEMS (64 * 12 * 49 * 49)   // 1,845,312

__device__ __forceinline__ unsigned short f2b(float f) {
    union { float f; unsigned int u; } v; v.f = f;
    return (unsigned short)((v.u + 0x7FFFu + ((v.u >> 16) & 1u)) >> 16);
}

__device__ __forceinline__ bf16x8 ld8(const unsigned short* p) {
    return *(const bf16x8*)p;
}

// async global->LDS, 16B/lane; lds dst is wave-uniform base + lane*16
__device__ __forceinline__ void gload16(const unsigned short* g, unsigned short* l) {
    __builtin_amdgcn_global_load_lds(
        (const __attribute__((address_space(1))) unsigned int*)g,
        (__attribute__((address_space(3))) unsigned int*)l, 16, 0, 0);
}

// bijective XCD-chunking swizzle (m204)
__device__ __forceinline__ int xcd_swizzle(int orig, int T) {
    int q = T >> 3, r = T & 7;
    int xcd = orig & 7, idx = orig >> 3;
    return (xcd < r ? xcd * (q + 1) : r * (q + 1) + (xcd - r) * q) + idx;
}

// ---------------- weight convert+transpose: Bt[n][k] = bf16(W[k][n]) --------
__global__ __launch_bounds__(256) void k_cvt_w(const float* __restrict__ wq,
        const float* __restrict__ wp, unsigned short* __restrict__ oq,
        unsigned short* __restrict__ op)
{
    int t = blockIdx.x * 256 + threadIdx.x;
    if (t < QKV_N * CH) {
        int n = t / CH, k = t - n * CH;
        oq[t] = f2b(wq[(size_t)k * QKV_N + n]);
    }
    if (t < CH * CH) {
        int n = t / CH, k = t - n * CH;
        op[t] = f2b(wp[(size_t)k * CH + n]);
    }
}

// ---------------- fused bias+mask table: bm[w][h][i][j] ----------------------
__global__ __launch_bounds__(256) void k_bm(const float* __restrict__ btab,
        const float* __restrict__ mask, float* __restrict__ bm)
{
    int t = blockIdx.x * 256 + threadIdx.x;
    if (t >= BM_ELEMS) return;
    int w   = t / (12 * 2401);
    int rem = t - w * 12 * 2401;
    int h   = rem / 2401;
    int ij  = rem - h * 2401;
    int i = ij / 49, j = ij - (ij / 49) * 49;
    int ih = i / 7, iw = i - (i / 7) * 7;
    int jh = j / 7, jw = j - (j / 7) * 7;
    int idx = (ih - jh + 6) * 13 + (iw - jw + 6);
    bm[t] = btab[idx * 12 + h] + mask[(size_t)w * 2401 + ij];
}

// ---------------- x fp32 -> bf16 (vectorized, grid-stride) -------------------
__global__ __launch_bounds__(256) void k_cvt(const float* __restrict__ in,
        unsigned short* __restrict__ outp, int n8)
{
    int stride = gridDim.x * 256;
    for (int i = blockIdx.x * 256 + threadIdx.x; i < n8; i += stride) {
        const float4* p = (const float4*)(in + (size_t)i * 8);
        float4 a = p[0], b = p[1];
        uint4 v;
        v.x = (unsigned)f2b(a.x) | ((unsigned)f2b(a.y) << 16);
        v.y = (unsigned)f2b(a.z) | ((unsigned)f2b(a.w) << 16);
        v.z = (unsigned)f2b(b.x) | ((unsigned)f2b(b.y) << 16);
        v.w = (unsigned)f2b(b.z) | ((unsigned)f2b(b.w) << 16);
        *(uint4*)(outp + (size_t)i * 8) = v;
    }
}

// ---------------- qkv GEMM: 256x128 block, 8 waves of 64x64 ------------------
// A bf16 [M][384], Bt bf16 n-major [1152][384]. BK=32. 3-buf LDS (72KB):
// per buf A 256x32 (8192 el) + B 128x32 (4096 el). chunk^(row&3) swizzle on
// gload source and ds_read. depth-2, vmcnt(6)/3/0.
__global__ __launch_bounds__(512, 4) void k_qkv(
        const unsigned short* __restrict__ A,
        const unsigned short* __restrict__ Bt,
        const float* __restrict__ bias,
        unsigned short* __restrict__ C, int M, int mtiles)
{
    extern __shared__ unsigned short smem[];   // 3 * 12288 elems
    const int wg = xcd_swizzle(blockIdx.x, mtiles * 9);
    const int m0 = (wg / 9) * 256;
    const int n0 = (wg % 9) * 128;
    const int tid = threadIdx.x;
    const int lane = tid & 63, wv = tid >> 6;
    const int wr = wv >> 1, wn = wv & 1;       // wave = 64x64 at (wr*64, wn*64)
    const int l15 = lane & 15, g = lane >> 4;

    f32x4 acc[4][4];
#pragma unroll
    for (int a = 0; a < 4; ++a)
#pragma unroll
        for (int b = 0; b < 4; ++b) acc[a][b] = (f32x4){0.f, 0.f, 0.f, 0.f};

    // staging: row r = tid>>2, src chunk = (tid&3)^(r&3). Wave w: rows w*16..15.
    const int srow = tid >> 2;
    const int schunk = ((tid & 3) ^ (srow & 3)) * 8;
    int ra0 = m0 + srow;        if (ra0 > M - 1) ra0 = M - 1;
    int ra1 = m0 + 128 + srow;  if (ra1 > M - 1) ra1 = M - 1;
    const unsigned short* a0p = A + (size_t)ra0 * CH + schunk;
    const unsigned short* a1p = A + (size_t)ra1 * CH + schunk;
    const unsigned short* bp  = Bt + (size_t)(n0 + srow) * CH + schunk;
    const int la0 = wv * 512;              // A rows w*16..15
    const int la1 = 4096 + wv * 512;       // A rows 128+w*16..15
    const int lb  = 8192 + wv * 512;       // B rows w*16..15

#define STAGE(kt, buf) do { unsigned short* pb = smem + (buf) * 12288;  \
        gload16(a0p + (kt), pb + la0);                                   \
        gload16(a1p + (kt), pb + la1);                                   \
        gload16(bp  + (kt), pb + lb);  } while (0)

#define COMPUTE(buf) do {                                                     \
        const unsigned short* pb = smem + (buf) * 12288;                      \
        bf16x8 af[4], bfr[4];                                                 \
        _Pragma("unroll")                                                     \
        for (int mt = 0; mt < 4; ++mt) {                                      \
            int row = wr * 64 + mt * 16 + l15;                                \
            af[mt] = ld8(pb + row * 32 + ((g ^ (row & 3)) * 8));              \
        }                                                                     \
        _Pragma("unroll")                                                     \
        for (int nt = 0; nt < 4; ++nt) {                                      \
            int row = wn * 64 + nt * 16 + l15;                                \
            bfr[nt] = ld8(pb + 8192 + row * 32 + ((g ^ (row & 3)) * 8));      \
        }                                                                     \
        __builtin_amdgcn_s_setprio(1);                                        \
        _Pragma("unroll")                                                     \
        for (int mt = 0; mt < 4; ++mt)                                        \
            _Pragma("unroll")                                                 \
            for (int nt = 0; nt < 4; ++nt)                                    \
                acc[mt][nt] = __builtin_amdgcn_mfma_f32_16x16x32_bf16(        \
                        af[mt], bfr[nt], acc[mt][nt], 0, 0, 0);               \
        __builtin_amdgcn_s_setprio(0);                                        \
    } while (0)

    const int nsteps = 12;                 // K=384, BK=32

    STAGE(0, 0);
    STAGE(32, 1);

    int cur = 0;
    for (int t = 0; t < nsteps - 2; ++t) {
        int pf = cur + 2; if (pf >= 3) pf -= 3;
        STAGE((t + 2) * 32, pf);
        __builtin_amdgcn_sched_barrier(0);
        asm volatile("s_waitcnt vmcnt(6)" ::: "memory");   // tile t's 3 done
        __builtin_amdgcn_sched_barrier(0);
        __builtin_amdgcn_s_barrier();
        __builtin_amdgcn_sched_barrier(0);
        COMPUTE(cur);
        __builtin_amdgcn_sched_barrier(0);
        __builtin_amdgcn_s_barrier();
        __builtin_amdgcn_sched_barrier(0);
        cur = (cur == 2) ? 0 : cur + 1;
    }
    asm volatile("s_waitcnt vmcnt(3)" ::: "memory");
    __builtin_amdgcn_sched_barrier(0);
    __builtin_amdgcn_s_barrier();
    __builtin_amdgcn_sched_barrier(0);
    COMPUTE(cur);
    __builtin_amdgcn_sched_barrier(0);
    __builtin_amdgcn_s_barrier();
    __builtin_amdgcn_sched_barrier(0);
    cur = (cur == 2) ? 0 : cur + 1;
    asm volatile("s_waitcnt vmcnt(0)" ::: "memory");
    __builtin_amdgcn_sched_barrier(0);
    __builtin_amdgcn_s_barrier();
    __builtin_amdgcn_sched_barrier(0);
    COMPUTE(cur);
#undef STAGE
#undef COMPUTE

    // ---- epilogue: scalar stores
#pragma unroll
    for (int mt = 0; mt < 4; ++mt)
#pragma unroll
        for (int nt = 0; nt < 4; ++nt) {
            int col = n0 + wn * 64 + nt * 16 + l15;
            float bb = bias[col];
#pragma unroll
            for (int r = 0; r < 4; ++r) {
                int row = m0 + wr * 64 + mt * 16 + g * 4 + r;
                if (row < M)
                    C[(size_t)row * QKV_N + col] = f2b(acc[mt][nt][r] + bb);
            }
        }
}

// ---------------- R15 8-wave GEMM (proj): C fp32 = A @ Bt^T + bias -----------
__global__ __launch_bounds__(512, 6) void k_proj(
        const unsigned short* __restrict__ A, int lda,
        const unsigned short* __restrict__ Bt, int K,
        const float* __restrict__ bias, float* __restrict__ Cf, int ldc,
        int M, int ntiles, int mtiles)
{
    __shared__ unsigned short As[3 * 4096];
    __shared__ unsigned short Bs[3 * 4096];
    const int wg = xcd_swizzle(blockIdx.x, mtiles * ntiles);
    const int m0 = (wg / ntiles) * 128;
    const int n0 = (wg % ntiles) * 128;
    const int tid = threadIdx.x;
    const int lane = tid & 63, wv = tid >> 6;
    const int wr = wv >> 2, wc = wv & 3;
    const int l15 = lane & 15, g = lane >> 4;

    f32x4 acc[4][2];
#pragma unroll
    for (int a = 0; a < 4; ++a)
#pragma unroll
        for (int b = 0; b < 2; ++b) acc[a][b] = (f32x4){0.f, 0.f, 0.f, 0.f};

    int arow = m0 + (tid >> 2); if (arow > M - 1) arow = M - 1;
    const unsigned short* aP = A + (size_t)arow * lda + (tid & 3) * 8;
    const unsigned short* bP = Bt + (size_t)(n0 + (tid >> 2)) * K + (tid & 3) * 8;
    const int lo = wv * 512;

#define STAGE(kt, buf) do {                                \
        gload16(aP + (kt), &As[(buf) * 4096 + lo]);        \
        gload16(bP + (kt), &Bs[(buf) * 4096 + lo]);        \
    } while (0)

#define COMPUTE(buf) do {                                                       \
        bf16x8 af[4], bfr[2];                                                   \
        _Pragma("unroll")                                                       \
        for (int mt = 0; mt < 4; ++mt)                                          \
            af[mt] = ld8(&As[(buf) * 4096 + (wr * 64 + mt * 16 + l15) * 32 + g * 8]); \
        _Pragma("unroll")                                                       \
        for (int nt = 0; nt < 2; ++nt)                                          \
            bfr[nt] = ld8(&Bs[(buf) * 4096 + (wc * 32 + nt * 16 + l15) * 32 + g * 8]); \
        __builtin_amdgcn_s_setprio(1);                                          \
        _Pragma("unroll")                                                       \
        for (int mt = 0; mt < 4; ++mt)                                          \
            _Pragma("unroll")                                                   \
            for (int nt = 0; nt < 2; ++nt)                                      \
                acc[mt][nt] = __builtin_amdgcn_mfma_f32_16x16x32_bf16(          \
                        af[mt], bfr[nt], acc[mt][nt], 0, 0, 0);                 \
        __builtin_amdgcn_s_setprio(0);                                          \
    } while (0)

    const int nsteps = K >> 5;

    STAGE(0, 0);
    STAGE(32, 1);

    int cur = 0;
    for (int t = 0; t < nsteps - 2; ++t) {
        int pf = cur + 2; if (pf >= 3) pf -= 3;
        STAGE((t + 2) * 32, pf);
        __builtin_amdgcn_sched_barrier(0);
        asm volatile("s_waitcnt vmcnt(4)" ::: "memory");
        __builtin_amdgcn_sched_barrier(0);
        __builtin_amdgcn_s_barrier();
        __builtin_amdgcn_sched_barrier(0);
        COMPUTE(cur);
        __builtin_amdgcn_sched_barrier(0);
        __builtin_amdgcn_s_barrier();
        __builtin_amdgcn_sched_barrier(0);
        cur = (cur == 2) ? 0 : cur + 1;
    }
    asm volatile("s_waitcnt vmcnt(2)" ::: "memory");
    __builtin_amdgcn_sched_barrier(0);
    __builtin_amdgcn_s_barrier();
    __builtin_amdgcn_sched_barrier(0);
    COMPUTE(cur);
    __builtin_amdgcn_sched_barrier(0);
    __builtin_amdgcn_s_barrier();
    __builtin_amdgcn_sched_barrier(0);
    cur = (cur == 2) ? 0 : cur + 1;
    asm volatile("s_waitcnt vmcnt(0)" ::: "memory");
    __builtin_amdgcn_sched_barrier(0);
    __builtin_amdgcn_s_barrier();
    __builtin_amdgcn_sched_barrier(0);
    COMPUTE(cur);
#undef STAGE
#undef COMPUTE

#pragma unroll
    for (int mt = 0; mt < 4; ++mt)
#pragma unroll
        for (int nt = 0; nt < 2; ++nt) {
            int col = n0 + wc * 32 + nt * 16 + l15;
            float bb = bias[col];
#pragma unroll
            for (int r = 0; r < 4; ++r) {
                int row = m0 + wr * 64 + mt * 16 + g * 4 + r;
                if (row < M)
                    Cf[(size_t)row * ldc + col] = acc[mt][nt][r] + bb;
            }
        }
}

// ---------------- attention: 1 wave per (window, head) -----------------------
__global__ __launch_bounds__(256) void k_attn(unsigned short* __restrict__ qkv,
        const float* __restrict__ bm)
{
    extern __shared__ unsigned short sm[];
    const int tid = threadIdx.x;
    const int lane = tid & 63, wv = tid >> 6;
    const int l15 = lane & 15, g = lane >> 4;
    const int pair = blockIdx.x * 4 + wv;
    const int winloc = pair / 12;
    const int h = pair - winloc * 12;
    const int wimg = winloc & 63;
    const int co = h * 32;
    unsigned short* Vt = sm + wv * 6048;     // [32][72]  V^T
    unsigned short* Pw = Vt + 32 * 72;       // [52][72]  P
    unsigned short* src = qkv + (size_t)winloc * SEQ_N * QKV_N;
    const float* bmh = bm + ((size_t)(wimg * 12 + h)) * 2401;

    for (int t = lane; t < 32 * 16; t += 64) {
        int c = t >> 4, kk = 48 + (t & 15);
        Vt[c * 72 + kk] = 0;
    }
    for (int t = lane; t < 49 * 4; t += 64) {
        int row = t >> 2, cb = (t & 3) * 8;
        const unsigned short* vp = src + (size_t)row * QKV_N + 768 + co + cb;
        ushort4 a = ((const ushort4*)vp)[0];
        ushort4 b = ((const ushort4*)vp)[1];
        Vt[(cb + 0) * 72 + row] = a.x; Vt[(cb + 1) * 72 + row] = a.y;
        Vt[(cb + 2) * 72 + row] = a.z; Vt[(cb + 3) * 72 + row] = a.w;
        Vt[(cb + 4) * 72 + row] = b.x; Vt[(cb + 5) * 72 + row] = b.y;
        Vt[(cb + 6) * 72 + row] = b.z; Vt[(cb + 7) * 72 + row] = b.w;
    }

    bf16x8 qf[4], kf[4];
#pragma unroll
    for (int mt = 0; mt < 4; ++mt) {
        int r = mt * 16 + l15; if (r > 48) r = 48;
        qf[mt] = ld8(src + (size_t)r * QKV_N + co + g * 8);
    }
#pragma unroll
    for (int nt = 0; nt < 4; ++nt) {
        int r = nt * 16 + l15; if (r > 48) r = 48;
        kf[nt] = ld8(src + (size_t)r * QKV_N + CH + co + g * 8);
    }

    f32x4 sa[4][4];
#pragma unroll
    for (int mt = 0; mt < 4; ++mt)
#pragma unroll
        for (int nt = 0; nt < 4; ++nt) sa[mt][nt] = (f32x4){0.f, 0.f, 0.f, 0.f};
#pragma unroll
    for (int mt = 0; mt < 4; ++mt)
#pragma unroll
        for (int nt = 0; nt < 4; ++nt)
            sa[mt][nt] = __builtin_amdgcn_mfma_f32_16x16x32_bf16(
                    qf[mt], kf[nt], sa[mt][nt], 0, 0, 0);

    int jj[4];
#pragma unroll
    for (int nt = 0; nt < 4; ++nt) jj[nt] = nt * 16 + l15;
    const float scale = 0.17677669529663687f;
#pragma unroll
    for (int mt = 0; mt < 4; ++mt) {
#pragma unroll
        for (int r = 0; r < 4; ++r) {
            int i = mt * 16 + g * 4 + r;
            int ic = i < 49 ? i : 48;
            const float* bmrow = bmh + ic * 49;
            float sv[4];
#pragma unroll
            for (int nt = 0; nt < 4; ++nt) {
                float s = sa[mt][nt][r];
                sv[nt] = (jj[nt] < 49) ? (s * scale + bmrow[jj[nt]]) : -1e30f;
            }
            float mx = fmaxf(fmaxf(sv[0], sv[1]), fmaxf(sv[2], sv[3]));
#pragma unroll
            for (int d = 1; d < 16; d <<= 1) mx = fmaxf(mx, __shfl_xor(mx, d));
            float sum = 0.f;
#pragma unroll
            for (int nt = 0; nt < 4; ++nt) { sv[nt] = __expf(sv[nt] - mx); sum += sv[nt]; }
#pragma unroll
            for (int d = 1; d < 16; d <<= 1) sum += __shfl_xor(sum, d);
            float inv = 1.0f / sum;
            if (i < 52) {
#pragma unroll
                for (int nt = 0; nt < 4; ++nt)
                    Pw[i * 72 + nt * 16 + l15] = f2b(sv[nt] * inv);
            }
        }
    }
    __syncthreads();

    f32x4 oa[4][2];
#pragma unroll
    for (int mt = 0; mt < 4; ++mt)
#pragma unroll
        for (int nt = 0; nt < 2; ++nt) oa[mt][nt] = (f32x4){0.f, 0.f, 0.f, 0.f};
#pragma unroll
    for (int ks = 0; ks < 2; ++ks) {
        bf16x8 pf[4];
#pragma unroll
        for (int mt = 0; mt < 4; ++mt) {
            int pr = mt * 16 + l15; if (pr > 51) pr = 51;
            pf[mt] = ld8(Pw + pr * 72 + ks * 32 + g * 8);
        }
#pragma unroll
        for (int nt = 0; nt < 2; ++nt) {
            bf16x8 vf = ld8(Vt + (nt * 16 + l15) * 72 + ks * 32 + g * 8);
#pragma unroll
            for (int mt = 0; mt < 4; ++mt)
                oa[mt][nt] = __builtin_amdgcn_mfma_f32_16x16x32_bf16(
                        pf[mt], vf, oa[mt][nt], 0, 0, 0);
        }
    }

#pragma unroll
    for (int mt = 0; mt < 4; ++mt)
#pragma unroll
        for (int r = 0; r < 4; ++r) {
            int i = mt * 16 + g * 4 + r;
            if (i < 49) {
#pragma unroll
                for (int nt = 0; nt < 2; ++nt)
                    src[(size_t)i * QKV_N + co + nt * 16 + l15] = f2b(oa[mt][nt][r]);
            }
        }
}

extern "C" void kernel_launch(void* const* d_in, const int* in_sizes, int n_in,
                              void* d_out, int out_size, void* d_ws, size_t ws_size,
                              hipStream_t stream) {
    const float* x      = (const float*)d_in[0];
    const float* mask   = (const float*)d_in[1];
    const float* qkv_w  = (const float*)d_in[2];
    const float* qkv_b  = (const float*)d_in[3];
    const float* proj_w = (const float*)d_in[4];
    const float* proj_b = (const float*)d_in[5];
    const float* btab   = (const float*)d_in[6];
    float* out = (float*)d_out;

    unsigned short* wq_bt = (unsigned short*)d_ws;
    unsigned short* wp_bt = wq_bt + QKV_N * CH;
    float*          bm    = (float*)(wp_bt + CH * CH);
    unsigned short* base  = (unsigned short*)(bm + BM_ELEMS);
    const size_t fixed = (size_t)(QKV_N * CH + CH * CH) * 2 + (size_t)BM_ELEMS * 4;
    const size_t unit  = (size_t)UNIT_ROWS * (CH + QKV_N) * 2;
    if (ws_size < fixed + unit) return;
    int upc = (int)((ws_size - fixed) / unit);
    if (upc > 64) upc = 64;
    unsigned short* xb  = base;
    unsigned short* qkv = base + (size_t)upc * UNIT_ROWS * CH;

    const int smem2 = 4 * 6048 * 2;   // 48,384 B -> 3 blocks/CU (attn)
    hipFuncSetAttribute(reinterpret_cast<const void*>(k_attn),
                        hipFuncAttributeMaxDynamicSharedMemorySize, smem2);
    const int smemQ = 3 * 12288 * 2;  // 73,728 B (qkv)
    hipFuncSetAttribute(reinterpret_cast<const void*>(k_qkv),
                        hipFuncAttributeMaxDynamicSharedMemorySize, smemQ);

    dim3 blk(256);
    k_cvt_w<<<dim3((QKV_N * CH + 255) / 256), blk, 0, stream>>>(qkv_w, proj_w, wq_bt, wp_bt);
    k_bm   <<<dim3((BM_ELEMS + 255) / 256), blk, 0, stream>>>(btab, mask, bm);

    for (int u0 = 0; u0 < 64; u0 += upc) {
        int units = (64 - u0) < upc ? (64 - u0) : upc;
        int m_base = u0 * UNIT_ROWS;
        int Mc = units * UNIT_ROWS;
        int mtilesQ = (Mc + 255) / 256;
        int mtilesP = (Mc + 127) / 128;
        k_cvt<<<dim3(2048), blk, 0, stream>>>(x + (size_t)m_base * CH, xb, Mc * 48);
        k_qkv<<<dim3(mtilesQ * 9), dim3(512), smemQ, stream>>>(
                xb, wq_bt, qkv_b, qkv, Mc, mtilesQ);
        k_attn<<<dim3(units * 192), blk, smem2, stream>>>(qkv, bm);
        k_proj<<<dim3(mtilesP * 3), dim3(512), 0, stream>>>(
                qkv, QKV_N, wp_bt, CH, proj_b, out + (size_t)m_base * CH,
                CH, Mc, 3, mtilesP);
    }
}

// Round 17
// 863.127 us; speedup vs baseline: 1.0758x; 1.0758x over previous
//
#include <hip/hip_runtime.h>
#include <hip/hip_bf16.h>

// WindowAttention (Swin) on MI355X — round 17
//   Base = R15 (918us best; R16's 64x64-wave qkv reverted — 390 vs 383).
//   Change (attn): bm table repacked fragment-ordered as
//   bm2[w][h][i][j15][4] float4 with -1e30 fill for j>=49. Softmax inner
//   loop: ONE lane-contiguous float4 load per (mt,r) instead of 4 scalar
//   dword gathers + j<49 select — 16 VMEM instr/thread instead of 64.
//   GEMMs (qkv+proj) = R15 k_gemm verbatim; cvt/cvt_w unchanged.

typedef __attribute__((ext_vector_type(8))) short bf16x8;
typedef __attribute__((ext_vector_type(4))) float f32x4;

#define SEQ_N  49
#define CH     384
#define QKV_N  1152
#define UNIT_ROWS 3136   // 64 windows * 49 rows
#define BM2_ELEMS (64 * 12 * 49 * 64)   // 2,408,448 floats (9.6 MB)

__device__ __forceinline__ unsigned short f2b(float f) {
    union { float f; unsigned int u; } v; v.f = f;
    return (unsigned short)((v.u + 0x7FFFu + ((v.u >> 16) & 1u)) >> 16);
}

__device__ __forceinline__ bf16x8 ld8(const unsigned short* p) {
    return *(const bf16x8*)p;
}

// async global->LDS, 16B/lane; lds dst is wave-uniform base + lane*16
__device__ __forceinline__ void gload16(const unsigned short* g, unsigned short* l) {
    __builtin_amdgcn_global_load_lds(
        (const __attribute__((address_space(1))) unsigned int*)g,
        (__attribute__((address_space(3))) unsigned int*)l, 16, 0, 0);
}

// bijective XCD-chunking swizzle (m204)
__device__ __forceinline__ int xcd_swizzle(int orig, int T) {
    int q = T >> 3, r = T & 7;
    int xcd = orig & 7, idx = orig >> 3;
    return (xcd < r ? xcd * (q + 1) : r * (q + 1) + (xcd - r) * q) + idx;
}

// ---------------- weight convert+transpose: Bt[n][k] = bf16(W[k][n]) --------
__global__ __launch_bounds__(256) void k_cvt_w(const float* __restrict__ wq,
        const float* __restrict__ wp, unsigned short* __restrict__ oq,
        unsigned short* __restrict__ op)
{
    int t = blockIdx.x * 256 + threadIdx.x;
    if (t < QKV_N * CH) {
        int n = t / CH, k = t - n * CH;
        oq[t] = f2b(wq[(size_t)k * QKV_N + n]);
    }
    if (t < CH * CH) {
        int n = t / CH, k = t - n * CH;
        op[t] = f2b(wp[(size_t)k * CH + n]);
    }
}

// ---------------- fragment-ordered bias+mask: bm2[w][h][i][j15][nt] ----------
// value for j = nt*16 + j15 ; j >= 49 -> -1e30 (kills pad cols, no branch)
__global__ __launch_bounds__(256) void k_bm(const float* __restrict__ btab,
        const float* __restrict__ mask, float* __restrict__ bm2)
{
    int t = blockIdx.x * 256 + threadIdx.x;
    if (t >= BM2_ELEMS) return;
    int w    = t / (12 * 49 * 64);
    int rem  = t - w * 12 * 49 * 64;
    int h    = rem / (49 * 64);
    int rem2 = rem - h * 49 * 64;
    int i    = rem2 >> 6;
    int s    = rem2 & 63;
    int j15  = s >> 2, nt = s & 3;
    int j    = nt * 16 + j15;
    float v = -1e30f;
    if (j < 49) {
        int ih = i / 7, iw = i - (i / 7) * 7;
        int jh = j / 7, jw = j - (j / 7) * 7;
        int idx = (ih - jh + 6) * 13 + (iw - jw + 6);
        v = btab[idx * 12 + h] + mask[(size_t)w * 2401 + i * 49 + j];
    }
    bm2[t] = v;
}

// ---------------- x fp32 -> bf16 (vectorized, grid-stride) -------------------
__global__ __launch_bounds__(256) void k_cvt(const float* __restrict__ in,
        unsigned short* __restrict__ outp, int n8)
{
    int stride = gridDim.x * 256;
    for (int i = blockIdx.x * 256 + threadIdx.x; i < n8; i += stride) {
        const float4* p = (const float4*)(in + (size_t)i * 8);
        float4 a = p[0], b = p[1];
        uint4 v;
        v.x = (unsigned)f2b(a.x) | ((unsigned)f2b(a.y) << 16);
        v.y = (unsigned)f2b(a.z) | ((unsigned)f2b(a.w) << 16);
        v.z = (unsigned)f2b(b.x) | ((unsigned)f2b(b.y) << 16);
        v.w = (unsigned)f2b(b.z) | ((unsigned)f2b(b.w) << 16);
        *(uint4*)(outp + (size_t)i * 8) = v;
    }
}

// ---------------- R15 8-wave GEMM: C[M][ldc] = A @ Bt^T + bias ---------------
// 128x128 tile, BK=32, 512 threads (8 waves, 64x32 each). 3-buf LDS, depth-2
// prefetch, counted vmcnt (per-wave 2 loads/tile -> vmcnt(4)/2/0).
template<int OUTF32>
__global__ __launch_bounds__(512, 6) void k_gemm(
        const unsigned short* __restrict__ A, int lda,
        const unsigned short* __restrict__ Bt, int K,
        const float* __restrict__ bias,
        unsigned short* __restrict__ Cb, float* __restrict__ Cf, int ldc,
        int M, int ntiles, int mtiles)
{
    __shared__ unsigned short As[3 * 4096];
    __shared__ unsigned short Bs[3 * 4096];
    const int wg = xcd_swizzle(blockIdx.x, mtiles * ntiles);
    const int m0 = (wg / ntiles) * 128;
    const int n0 = (wg % ntiles) * 128;
    const int tid = threadIdx.x;
    const int lane = tid & 63, wv = tid >> 6;
    const int wr = wv >> 2, wc = wv & 3;
    const int l15 = lane & 15, g = lane >> 4;

    f32x4 acc[4][2];
#pragma unroll
    for (int a = 0; a < 4; ++a)
#pragma unroll
        for (int b = 0; b < 2; ++b) acc[a][b] = (f32x4){0.f, 0.f, 0.f, 0.f};

    int arow = m0 + (tid >> 2); if (arow > M - 1) arow = M - 1;
    const unsigned short* aP = A + (size_t)arow * lda + (tid & 3) * 8;
    const unsigned short* bP = Bt + (size_t)(n0 + (tid >> 2)) * K + (tid & 3) * 8;
    const int lo = wv * 512;

#define STAGE(kt, buf) do {                                \
        gload16(aP + (kt), &As[(buf) * 4096 + lo]);        \
        gload16(bP + (kt), &Bs[(buf) * 4096 + lo]);        \
    } while (0)

#define COMPUTE(buf) do {                                                       \
        bf16x8 af[4], bfr[2];                                                   \
        _Pragma("unroll")                                                       \
        for (int mt = 0; mt < 4; ++mt)                                          \
            af[mt] = ld8(&As[(buf) * 4096 + (wr * 64 + mt * 16 + l15) * 32 + g * 8]); \
        _Pragma("unroll")                                                       \
        for (int nt = 0; nt < 2; ++nt)                                          \
            bfr[nt] = ld8(&Bs[(buf) * 4096 + (wc * 32 + nt * 16 + l15) * 32 + g * 8]); \
        __builtin_amdgcn_s_setprio(1);                                          \
        _Pragma("unroll")                                                       \
        for (int mt = 0; mt < 4; ++mt)                                          \
            _Pragma("unroll")                                                   \
            for (int nt = 0; nt < 2; ++nt)                                      \
                acc[mt][nt] = __builtin_amdgcn_mfma_f32_16x16x32_bf16(          \
                        af[mt], bfr[nt], acc[mt][nt], 0, 0, 0);                 \
        __builtin_amdgcn_s_setprio(0);                                          \
    } while (0)

    const int nsteps = K >> 5;           // 12 (qkv) or 36 (proj)

    STAGE(0, 0);
    STAGE(32, 1);

    int cur = 0;
    for (int t = 0; t < nsteps - 2; ++t) {
        int pf = cur + 2; if (pf >= 3) pf -= 3;
        STAGE((t + 2) * 32, pf);
        __builtin_amdgcn_sched_barrier(0);
        asm volatile("s_waitcnt vmcnt(4)" ::: "memory");
        __builtin_amdgcn_sched_barrier(0);
        __builtin_amdgcn_s_barrier();
        __builtin_amdgcn_sched_barrier(0);
        COMPUTE(cur);
        __builtin_amdgcn_sched_barrier(0);
        __builtin_amdgcn_s_barrier();
        __builtin_amdgcn_sched_barrier(0);
        cur = (cur == 2) ? 0 : cur + 1;
    }
    asm volatile("s_waitcnt vmcnt(2)" ::: "memory");
    __builtin_amdgcn_sched_barrier(0);
    __builtin_amdgcn_s_barrier();
    __builtin_amdgcn_sched_barrier(0);
    COMPUTE(cur);
    __builtin_amdgcn_sched_barrier(0);
    __builtin_amdgcn_s_barrier();
    __builtin_amdgcn_sched_barrier(0);
    cur = (cur == 2) ? 0 : cur + 1;
    asm volatile("s_waitcnt vmcnt(0)" ::: "memory");
    __builtin_amdgcn_sched_barrier(0);
    __builtin_amdgcn_s_barrier();
    __builtin_amdgcn_sched_barrier(0);
    COMPUTE(cur);
#undef STAGE
#undef COMPUTE

#pragma unroll
    for (int mt = 0; mt < 4; ++mt)
#pragma unroll
        for (int nt = 0; nt < 2; ++nt) {
            int col = n0 + wc * 32 + nt * 16 + l15;
            float bb = bias[col];
#pragma unroll
            for (int r = 0; r < 4; ++r) {
                int row = m0 + wr * 64 + mt * 16 + g * 4 + r;
                if (row < M) {
                    if (OUTF32)
                        Cf[(size_t)row * ldc + col] = acc[mt][nt][r] + bb;
                    else
                        Cb[(size_t)row * ldc + col] = f2b(acc[mt][nt][r] + bb);
                }
            }
        }
}

// ---------------- attention: 1 wave per (window, head) -----------------------
// Per-wave LDS: Vt [32][72] + Pw [52][72] = 12,096 B -> 48,384 B/block
// -> 3 blocks/CU. Bias+mask via fragment-ordered bm2 float4 loads.
__global__ __launch_bounds__(256) void k_attn(unsigned short* __restrict__ qkv,
        const float* __restrict__ bm2)
{
    extern __shared__ unsigned short sm[];
    const int tid = threadIdx.x;
    const int lane = tid & 63, wv = tid >> 6;
    const int l15 = lane & 15, g = lane >> 4;
    const int pair = blockIdx.x * 4 + wv;
    const int winloc = pair / 12;
    const int h = pair - winloc * 12;
    const int wimg = winloc & 63;
    const int co = h * 32;
    unsigned short* Vt = sm + wv * 6048;     // [32][72]  V^T
    unsigned short* Pw = Vt + 32 * 72;       // [52][72]  P
    unsigned short* src = qkv + (size_t)winloc * SEQ_N * QKV_N;
    const float* bm2h = bm2 + ((size_t)(wimg * 12 + h)) * (49 * 64);

    for (int t = lane; t < 32 * 16; t += 64) {
        int c = t >> 4, kk = 48 + (t & 15);
        Vt[c * 72 + kk] = 0;
    }
    for (int t = lane; t < 49 * 4; t += 64) {
        int row = t >> 2, cb = (t & 3) * 8;
        const unsigned short* vp = src + (size_t)row * QKV_N + 768 + co + cb;
        ushort4 a = ((const ushort4*)vp)[0];
        ushort4 b = ((const ushort4*)vp)[1];
        Vt[(cb + 0) * 72 + row] = a.x; Vt[(cb + 1) * 72 + row] = a.y;
        Vt[(cb + 2) * 72 + row] = a.z; Vt[(cb + 3) * 72 + row] = a.w;
        Vt[(cb + 4) * 72 + row] = b.x; Vt[(cb + 5) * 72 + row] = b.y;
        Vt[(cb + 6) * 72 + row] = b.z; Vt[(cb + 7) * 72 + row] = b.w;
    }

    bf16x8 qf[4], kf[4];
#pragma unroll
    for (int mt = 0; mt < 4; ++mt) {
        int r = mt * 16 + l15; if (r > 48) r = 48;
        qf[mt] = ld8(src + (size_t)r * QKV_N + co + g * 8);
    }
#pragma unroll
    for (int nt = 0; nt < 4; ++nt) {
        int r = nt * 16 + l15; if (r > 48) r = 48;
        kf[nt] = ld8(src + (size_t)r * QKV_N + CH + co + g * 8);
    }

    f32x4 sa[4][4];
#pragma unroll
    for (int mt = 0; mt < 4; ++mt)
#pragma unroll
        for (int nt = 0; nt < 4; ++nt) sa[mt][nt] = (f32x4){0.f, 0.f, 0.f, 0.f};
#pragma unroll
    for (int mt = 0; mt < 4; ++mt)
#pragma unroll
        for (int nt = 0; nt < 4; ++nt)
            sa[mt][nt] = __builtin_amdgcn_mfma_f32_16x16x32_bf16(
                    qf[mt], kf[nt], sa[mt][nt], 0, 0, 0);

    const float scale = 0.17677669529663687f;
#pragma unroll
    for (int mt = 0; mt < 4; ++mt) {
#pragma unroll
        for (int r = 0; r < 4; ++r) {
            int i = mt * 16 + g * 4 + r;
            int ic = i < 49 ? i : 48;
            float4 bv = *(const float4*)(bm2h + (size_t)ic * 64 + l15 * 4);
            float sv[4];
            sv[0] = sa[mt][0][r] * scale + bv.x;
            sv[1] = sa[mt][1][r] * scale + bv.y;
            sv[2] = sa[mt][2][r] * scale + bv.z;
            sv[3] = sa[mt][3][r] * scale + bv.w;
            float mx = fmaxf(fmaxf(sv[0], sv[1]), fmaxf(sv[2], sv[3]));
#pragma unroll
            for (int d = 1; d < 16; d <<= 1) mx = fmaxf(mx, __shfl_xor(mx, d));
            float sum = 0.f;
#pragma unroll
            for (int nt = 0; nt < 4; ++nt) { sv[nt] = __expf(sv[nt] - mx); sum += sv[nt]; }
#pragma unroll
            for (int d = 1; d < 16; d <<= 1) sum += __shfl_xor(sum, d);
            float inv = 1.0f / sum;
            if (i < 52) {
#pragma unroll
                for (int nt = 0; nt < 4; ++nt)
                    Pw[i * 72 + nt * 16 + l15] = f2b(sv[nt] * inv);
            }
        }
    }
    __syncthreads();

    f32x4 oa[4][2];
#pragma unroll
    for (int mt = 0; mt < 4; ++mt)
#pragma unroll
        for (int nt = 0; nt < 2; ++nt) oa[mt][nt] = (f32x4){0.f, 0.f, 0.f, 0.f};
#pragma unroll
    for (int ks = 0; ks < 2; ++ks) {
        bf16x8 pf[4];
#pragma unroll
        for (int mt = 0; mt < 4; ++mt) {
            int pr = mt * 16 + l15; if (pr > 51) pr = 51;
            pf[mt] = ld8(Pw + pr * 72 + ks * 32 + g * 8);
        }
#pragma unroll
        for (int nt = 0; nt < 2; ++nt) {
            bf16x8 vf = ld8(Vt + (nt * 16 + l15) * 72 + ks * 32 + g * 8);
#pragma unroll
            for (int mt = 0; mt < 4; ++mt)
                oa[mt][nt] = __builtin_amdgcn_mfma_f32_16x16x32_bf16(
                        pf[mt], vf, oa[mt][nt], 0, 0, 0);
        }
    }

#pragma unroll
    for (int mt = 0; mt < 4; ++mt)
#pragma unroll
        for (int r = 0; r < 4; ++r) {
            int i = mt * 16 + g * 4 + r;
            if (i < 49) {
#pragma unroll
                for (int nt = 0; nt < 2; ++nt)
                    src[(size_t)i * QKV_N + co + nt * 16 + l15] = f2b(oa[mt][nt][r]);
            }
        }
}

extern "C" void kernel_launch(void* const* d_in, const int* in_sizes, int n_in,
                              void* d_out, int out_size, void* d_ws, size_t ws_size,
                              hipStream_t stream) {
    const float* x      = (const float*)d_in[0];
    const float* mask   = (const float*)d_in[1];
    const float* qkv_w  = (const float*)d_in[2];
    const float* qkv_b  = (const float*)d_in[3];
    const float* proj_w = (const float*)d_in[4];
    const float* proj_b = (const float*)d_in[5];
    const float* btab   = (const float*)d_in[6];
    float* out = (float*)d_out;

    unsigned short* wq_bt = (unsigned short*)d_ws;
    unsigned short* wp_bt = wq_bt + QKV_N * CH;
    float*          bm2   = (float*)(wp_bt + CH * CH);
    unsigned short* base  = (unsigned short*)(bm2 + BM2_ELEMS);
    const size_t fixed = (size_t)(QKV_N * CH + CH * CH) * 2 + (size_t)BM2_ELEMS * 4;
    const size_t unit  = (size_t)UNIT_ROWS * (CH + QKV_N) * 2;
    if (ws_size < fixed + unit) return;
    int upc = (int)((ws_size - fixed) / unit);
    if (upc > 64) upc = 64;
    unsigned short* xb  = base;
    unsigned short* qkv = base + (size_t)upc * UNIT_ROWS * CH;

    const int smem2 = 4 * 6048 * 2;   // 48,384 B -> 3 blocks/CU (attn)
    hipFuncSetAttribute(reinterpret_cast<const void*>(k_attn),
                        hipFuncAttributeMaxDynamicSharedMemorySize, smem2);

    dim3 blk(256);
    k_cvt_w<<<dim3((QKV_N * CH + 255) / 256), blk, 0, stream>>>(qkv_w, proj_w, wq_bt, wp_bt);
    k_bm   <<<dim3((BM2_ELEMS + 255) / 256), blk, 0, stream>>>(btab, mask, bm2);

    for (int u0 = 0; u0 < 64; u0 += upc) {
        int units = (64 - u0) < upc ? (64 - u0) : upc;
        int m_base = u0 * UNIT_ROWS;
        int Mc = units * UNIT_ROWS;
        int mtiles = (Mc + 127) / 128;
        k_cvt<<<dim3(2048), blk, 0, stream>>>(x + (size_t)m_base * CH, xb, Mc * 48);
        k_gemm<0><<<dim3(mtiles * 9), dim3(512), 0, stream>>>(
                xb, CH, wq_bt, CH, qkv_b, qkv, nullptr, QKV_N, Mc, 9, mtiles);
        k_attn<<<dim3(units * 192), blk, smem2, stream>>>(qkv, bm2);
        k_gemm<1><<<dim3(mtiles * 3), dim3(512), 0, stream>>>(
                qkv, QKV_N, wp_bt, CH, proj_b, nullptr, out + (size_t)m_base * CH,
                CH, Mc, 3, mtiles);
    }
}